// Round 2
// baseline (68.591 us; speedup 1.0000x reference)
//
#include <hip/hip_runtime.h>

#define DIM   128
#define PLANE (DIM*DIM)
#define TD    8

// Load one input plane's 3 tap-rows (cols wq-1 .. wq+8) into registers.
__device__ __forceinline__ void load_rows(const float* __restrict__ xb, int p,
    int ro0, int ro1, int ro2, int wq, int cm, int cp, float (&r)[3][10])
{
    const float* xp = xb + (size_t)((p & (DIM - 1)) * PLANE);
    const int ro[3] = {ro0, ro1, ro2};
#pragma unroll
    for (int ch = 0; ch < 3; ++ch) {
        const float* rp = xp + ro[ch];
        const float4 a = *(const float4*)(rp + wq);
        const float4 b = *(const float4*)(rp + wq + 4);
        r[ch][0] = rp[cm];                // x[wq-1] (wrapped)
        r[ch][1] = a.x; r[ch][2] = a.y; r[ch][3] = a.z; r[ch][4] = a.w;
        r[ch][5] = b.x; r[ch][6] = b.y; r[ch][7] = b.z; r[ch][8] = b.w;
        r[ch][9] = rp[cp];                // x[wq+8] (wrapped)
    }
}

__global__ __launch_bounds__(256, 4) void conv3d_circ_reg(
    const float* __restrict__ x, const float* __restrict__ kern,
    float* __restrict__ out)
{
    const int tid = threadIdx.x;
    const int bid = blockIdx.x;
    const int b  = bid >> 7;          // 8 batches
    const int ht = (bid >> 4) & 7;    // 8 h-tiles of 16
    const int dt = bid & 15;          // 16 d-chunks of 8
    const int h0 = ht * 16;
    const int d0 = dt * TD;

    const int wq = (tid & 15) * 8;    // 8 outputs along w
    const int hg = h0 + (tid >> 4);   // this thread's h row
    const int cm = (wq - 1) & (DIM - 1);
    const int cp = (wq + 8) & (DIM - 1);
    const int ro0 = ((hg - 1) & (DIM - 1)) * DIM;
    const int ro1 = hg * DIM;
    const int ro2 = ((hg + 1) & (DIM - 1)) * DIM;

    // taps -> uniform loads -> SGPRs
    float K0[9], K1[9], K2[9];
#pragma unroll
    for (int i = 0; i < 9; ++i) { K0[i] = kern[i]; K1[i] = kern[9 + i]; K2[i] = kern[18 + i]; }

    const float* xb = x + (size_t)b * (DIM * PLANE);
    float* ob = out + (size_t)b * (DIM * PLANE) + (size_t)hg * DIM + wq;

    float rA[3][10], rB[3][10];
    float accA[8], accB[8];           // accA -> out(p-1), accB -> out(p)
#pragma unroll
    for (int j = 0; j < 8; ++j) { accA[j] = 0.f; accB[j] = 0.f; }

    load_rows(xb, d0 - 1, ro0, ro1, ro2, wq, cm, cp, rA);

    // Plane p contributes: K2 -> out(p-1), K1 -> out(p), K0 -> out(p+1).
#define STEP(RC, RN, I, DOLOAD)                                               \
    {                                                                         \
        const int p = d0 - 1 + (I);                                           \
        if (DOLOAD) load_rows(xb, p + 1, ro0, ro1, ro2, wq, cm, cp, RN);      \
        float c0[8];                                                          \
        _Pragma("unroll") for (int j = 0; j < 8; ++j) c0[j] = 0.f;            \
        _Pragma("unroll") for (int ch = 0; ch < 3; ++ch)                      \
        _Pragma("unroll") for (int cw = 0; cw < 3; ++cw) {                    \
            const float k0 = K0[ch * 3 + cw];                                 \
            const float k1 = K1[ch * 3 + cw];                                 \
            const float k2 = K2[ch * 3 + cw];                                 \
            _Pragma("unroll") for (int j = 0; j < 8; ++j) {                   \
                const float xv = RC[ch][j + cw];                              \
                accA[j] = fmaf(k2, xv, accA[j]);                              \
                accB[j] = fmaf(k1, xv, accB[j]);                              \
                c0[j]   = fmaf(k0, xv, c0[j]);                                \
            }                                                                 \
        }                                                                     \
        if ((I) >= 2) {                                                       \
            float* op = ob + (size_t)(p - 1) * PLANE;                         \
            *(float4*)(op)     = make_float4(accA[0], accA[1], accA[2], accA[3]); \
            *(float4*)(op + 4) = make_float4(accA[4], accA[5], accA[6], accA[7]); \
        }                                                                     \
        _Pragma("unroll") for (int j = 0; j < 8; ++j) { accA[j] = accB[j]; accB[j] = c0[j]; } \
    }

#pragma unroll 1
    for (int i = 0; i < 8; i += 2) {
        STEP(rA, rB, i, true);
        STEP(rB, rA, i + 1, true);
    }
    STEP(rA, rB, 8, true);
    STEP(rB, rA, 9, false);
#undef STEP
}

extern "C" void kernel_launch(void* const* d_in, const int* in_sizes, int n_in,
                              void* d_out, int out_size, void* d_ws, size_t ws_size,
                              hipStream_t stream) {
    const float* x    = (const float*)d_in[0];
    const float* kern = (const float*)d_in[1];
    float*       out  = (float*)d_out;
    // 8 batches x 8 h-tiles(16) x 16 d-chunks(8) = 1024 blocks
    conv3d_circ_reg<<<dim3(1024), dim3(256), 0, stream>>>(x, kern, out);
}